// Round 1
// baseline (508.718 us; speedup 1.0000x reference)
//
#include <hip/hip_runtime.h>
#include <math.h>

#define N 8192
#define H 128
#define NEV 64
#define SS 20
#define MAXD 512
#define RPB 32   // rows per block in k_emb

// ---------------------------------------------------------------------------
// k_emb: h_tab[n][c] = sum_c' emb[n][c'] * W_h[c][c'] + b_h[c]
//        z_out[n] = emb[n] (copy), d0/d1[n] = emb[n] . (W_om[k][:H]+W_om[k][H:])
// 512 threads: c = tid&127, s = tid>>7 owns W_h[c][s*32..s*32+31] in registers.
// ---------------------------------------------------------------------------
__global__ __launch_bounds__(512) void k_emb(
    const float* __restrict__ emb, const float* __restrict__ W_h,
    const float* __restrict__ b_h, const float* __restrict__ W_om,
    float* __restrict__ h_tab, float* __restrict__ z_out,
    float* __restrict__ d0, float* __restrict__ d1)
{
    const int tid = threadIdx.x;
    const int c = tid & 127;
    const int s = tid >> 7;             // 0..3
    const int r0 = blockIdx.x * RPB;

    __shared__ __align__(16) float z4[4 * 128];
    __shared__ float pr[8 * 128];       // [s][rr][c]

    float whr[32];
#pragma unroll
    for (int i = 0; i < 32; ++i) whr[i] = W_h[c * H + s * 32 + i];
    const float bh_c = b_h[c];

    const int lane = tid & 63;
    const int wid = tid >> 6;           // 0..7 (waves)
    const int kof = (wid >= 4) ? 256 : 0;
    const float wk_l = W_om[kof + lane]      + W_om[kof + 128 + lane];
    const float wk_h = W_om[kof + 64 + lane] + W_om[kof + 192 + lane];

    for (int b = 0; b < RPB / 4; ++b) {
        const int rbase = r0 + b * 4;
        __syncthreads();                           // protect z4/pr reuse
        const float zv = emb[(size_t)rbase * H + tid];
        z4[tid] = zv;
        z_out[(size_t)rbase * H + tid] = zv;
        __syncthreads();

        // h partial dots
#pragma unroll
        for (int rr = 0; rr < 4; ++rr) {
            float a = 0.f;
#pragma unroll
            for (int i4 = 0; i4 < 8; ++i4) {
                const float4 zz = *(const float4*)&z4[rr * 128 + s * 32 + i4 * 4];
                a += zz.x * whr[i4 * 4] + zz.y * whr[i4 * 4 + 1] +
                     zz.z * whr[i4 * 4 + 2] + zz.w * whr[i4 * 4 + 3];
            }
            pr[(s * 4 + rr) * 128 + c] = a;
        }

        // d0/d1: one wave per row
        {
            const int rr = wid & 3;
            float val = z4[rr * 128 + lane] * wk_l + z4[rr * 128 + 64 + lane] * wk_h;
#pragma unroll
            for (int off = 32; off > 0; off >>= 1) val += __shfl_xor(val, off);
            if (lane == 0) {
                if (wid < 4) d0[rbase + rr] = val;
                else         d1[rbase + rr] = val;
            }
        }
        __syncthreads();
        // h finalize: rr = s
        {
            const int rr = s;
            const float h = pr[(0 * 4 + rr) * 128 + c] + pr[(1 * 4 + rr) * 128 + c] +
                            pr[(2 * 4 + rr) * 128 + c] + pr[(3 * 4 + rr) * 128 + c] + bh_c;
            h_tab[(size_t)(rbase + rr) * H + c] = h;
        }
    }
}

// ---------------------------------------------------------------------------
// k_nbr: compact neighbor lists for the 128 (event,side) rows.
// slot = e*2+side; side0 -> row v[e] (updates z[v]), side1 -> row u[e].
// ---------------------------------------------------------------------------
__global__ __launch_bounds__(256) void k_nbr(
    const int* __restrict__ u, const int* __restrict__ v,
    const float* __restrict__ A, const float* __restrict__ S,
    int* __restrict__ deg, float* __restrict__ sumv,
    int* __restrict__ nbr_i, float* __restrict__ nbr_e)
{
    const int slot = blockIdx.x;
    const int e = slot >> 1, side = slot & 1;
    const int row = (side == 0) ? v[e] : u[e];
    const size_t base = (size_t)row * N;
    const int tid = threadIdx.x;
    float lsum = 0.f;
    for (int j = tid; j < N; j += 256) {
        if (A[base + j] > 0.f) {
            const float ev = expf(S[base + j]);
            lsum += ev;
            const int p = atomicAdd(&deg[slot], 1);
            if (p < MAXD) {
                nbr_i[slot * MAXD + p] = j;
                nbr_e[slot * MAXD + p] = ev;
            }
        }
    }
    __shared__ float rs[256];
    rs[tid] = lsum;
    __syncthreads();
    for (int off = 128; off > 0; off >>= 1) {
        if (tid < off) rs[tid] += rs[tid + off];
        __syncthreads();
    }
    if (tid == 0) sumv[slot] = rs[0];
}

// ---------------------------------------------------------------------------
// k_lam: lam[b] = psi_k * log1p(exp(clip((0.5*(dk[u]+dk[v])+b_om[k])/psi_k)))
// ---------------------------------------------------------------------------
__global__ __launch_bounds__(64) void k_lam(
    const int* __restrict__ u, const int* __restrict__ v, const int* __restrict__ k,
    const float* __restrict__ d0, const float* __restrict__ d1,
    const float* __restrict__ psi, const float* __restrict__ b_om,
    float* __restrict__ out)
{
    const int b = threadIdx.x;
    if (b < NEV) {
        const int kk = k[b];
        const float* dk = kk ? d1 : d0;
        const float g = 0.5f * (dk[u[b]] + dk[v[b]]) + b_om[kk];
        const float ps = psi[kk];
        const float x = fminf(75.f, fmaxf(-75.f, g / ps));
        out[b] = ps * log1pf(expf(x));
    }
}

// ---------------------------------------------------------------------------
// k_surv: L_surv[s] = sum_b (2*(ru0+ru1)+rv1) / SS
// ---------------------------------------------------------------------------
__global__ __launch_bounds__(64) void k_surv(
    const int* __restrict__ u, const int* __restrict__ v,
    const int* __restrict__ u_o, const int* __restrict__ v_o,
    const float* __restrict__ d0, const float* __restrict__ d1,
    const float* __restrict__ psi, const float* __restrict__ b_om,
    float* __restrict__ out)
{
    const int s = blockIdx.x;   // 0..SS-1
    const int b = threadIdx.x;  // 0..63
    const float p0 = psi[0], p1 = psi[1], bo0 = b_om[0], bo1 = b_om[1];
    const int vo = v_o[b * SS + s], uo = u_o[b * SS + s];
    float g, x;
    g = 0.5f * (d0[u[b]] + d0[vo]) + bo0; x = fminf(75.f, fmaxf(-75.f, g / p0));
    const float ru0 = p0 * log1pf(expf(x));
    g = 0.5f * (d1[u[b]] + d1[vo]) + bo1; x = fminf(75.f, fmaxf(-75.f, g / p1));
    const float ru1 = p1 * log1pf(expf(x));
    g = 0.5f * (d1[v[b]] + d1[uo]) + bo1; x = fminf(75.f, fmaxf(-75.f, g / p1));
    const float rv1 = p1 * log1pf(expf(x));
    float val = 2.f * (ru0 + ru1) + rv1;
#pragma unroll
    for (int off = 32; off > 0; off >>= 1) val += __shfl_xor(val, off);
    if (b == 0) out[s] = val / (float)SS;
}

// ---------------------------------------------------------------------------
// k_seq: the sequential 64-event scan. One block, 512 threads.
// r=0 -> row v[e]: hs from nbrs of v (side0), dt = t - let[u]   (crossed!)
// r=1 -> row u[e]: hs from nbrs of u (side1), dt = t - let[v]
// W_S/W_R/W_h held in registers: thread (c = tid&127, s = tid>>7) owns
// row c, chunk c' = s*32..s*32+31 of each matrix.
// ---------------------------------------------------------------------------
__global__ __launch_bounds__(512) void k_seq(
    const int* __restrict__ u, const int* __restrict__ v, const float* __restrict__ t,
    const float* __restrict__ lastt,
    const float* __restrict__ W_S, const float* __restrict__ W_R,
    const float* __restrict__ W_t, const float* __restrict__ W_h,
    const float* __restrict__ b_h,
    const int* __restrict__ deg, const float* __restrict__ sumv,
    const int* __restrict__ nbr_i, const float* __restrict__ nbr_e,
    float* __restrict__ h_tab, float* __restrict__ z_out)
{
    const int tid = threadIdx.x;
    const int c = tid & 127;
    const int s = tid >> 7;                 // 0..3

    __shared__ float let_lds[N];            // 32 KB
    __shared__ __align__(16) float hz[128 * 4];   // [c']{hs0,hs1,z_v,z_u}
    __shared__ float red[2 * 4 * 128];      // phase-A group maxima
    __shared__ float pr[8 * 128];           // [(s*2+r)][c] partials
    __shared__ __align__(8) float znw[128 * 2];   // [c']{znew_v, znew_u}

    float wsr[32], wrr[32], whr[32];
#pragma unroll
    for (int i = 0; i < 32; ++i) {
        wsr[i] = W_S[c * H + s * 32 + i];
        wrr[i] = W_R[c * H + s * 32 + i];
        whr[i] = W_h[c * H + s * 32 + i];
    }
    const float wt_c = W_t[c];
    const float bh_c = b_h[c];

    for (int i = tid; i < N; i += 512) let_lds[i] = lastt[i];
    __syncthreads();

    for (int e = 0; e < NEV; ++e) {
        const int uu = u[e], vv = v[e];
        const float tt = t[e];

        // ---- Phase A: per-column max of q_j * h[j][c] over neighbors ----
#pragma unroll
        for (int side = 0; side < 2; ++side) {
            const int slot = e * 2 + side;
            const int d = min(deg[slot], MAXD);
            const float rinv = 1.0f / (sumv[slot] + 1e-7f);
            float m = -INFINITY;
            for (int j0 = s; j0 < d; j0 += 4) {
                const int j = nbr_i[slot * MAXD + j0];
                const float q = nbr_e[slot * MAXD + j0] * rinv;
                m = fmaxf(m, q * h_tab[(size_t)j * H + c]);
            }
            red[(side * 4 + s) * 128 + c] = m;
        }
        __syncthreads();
        if (tid < 256) {
            const int side = tid >> 7;
            const int slot = e * 2 + side;
            const int d = deg[slot];
            const float m = fmaxf(fmaxf(red[(side * 4 + 0) * 128 + c], red[(side * 4 + 1) * 128 + c]),
                                  fmaxf(red[(side * 4 + 2) * 128 + c], red[(side * 4 + 3) * 128 + c]));
            // monotonicity: max_j sigmoid(x_j) == sigmoid(max_j x_j)
            hz[c * 4 + side] = (d > 0) ? 1.0f / (1.0f + __expf(-m)) : 0.0f;
        } else {
            const int r = (tid >> 7) & 1;   // 0 -> row v, 1 -> row u
            const int row = (r == 0) ? vv : uu;
            hz[c * 4 + 2 + r] = z_out[(size_t)row * H + c];
        }
        __syncthreads();

        // ---- Phase B: g[r][c] = hs_r.W_S[c] + z_row_r.W_R[c] (+ dt*W_t) ----
        {
            float a0 = 0.f, a1 = 0.f;
#pragma unroll
            for (int i = 0; i < 32; ++i) {
                const float4 vz = *(const float4*)&hz[(s * 32 + i) * 4];
                a0 += vz.x * wsr[i] + vz.z * wrr[i];
                a1 += vz.y * wsr[i] + vz.w * wrr[i];
            }
            pr[(s * 2 + 0) * 128 + c] = a0;
            pr[(s * 2 + 1) * 128 + c] = a1;
        }
        __syncthreads();
        if (tid < 256) {
            const int r = tid >> 7;
            float g = pr[(0 * 2 + r) * 128 + c] + pr[(1 * 2 + r) * 128 + c] +
                      pr[(2 * 2 + r) * 128 + c] + pr[(3 * 2 + r) * 128 + c];
            const float dt = tt - ((r == 0) ? let_lds[uu] : let_lds[vv]);
            g += dt * wt_c;
            znw[c * 2 + r] = 1.0f / (1.0f + __expf(-g));
        }
        __syncthreads();

        // ---- Phase C: refresh h rows for the updated z rows ----
        {
            float a0 = 0.f, a1 = 0.f;
#pragma unroll
            for (int i = 0; i < 32; ++i) {
                const float2 zz = *(const float2*)&znw[(s * 32 + i) * 2];
                a0 += zz.x * whr[i];
                a1 += zz.y * whr[i];
            }
            pr[(s * 2 + 0) * 128 + c] = a0;
            pr[(s * 2 + 1) * 128 + c] = a1;
        }
        __syncthreads();
        if (tid < 256) {
            const int r = tid >> 7;
            const int row = (r == 0) ? vv : uu;
            if (!(uu == vv && r == 0)) {       // duplicate rows: last index wins
                const float hval = pr[(0 * 2 + r) * 128 + c] + pr[(1 * 2 + r) * 128 + c] +
                                   pr[(2 * 2 + r) * 128 + c] + pr[(3 * 2 + r) * 128 + c] + bh_c;
                z_out[(size_t)row * H + c] = znw[c * 2 + r];
                h_tab[(size_t)row * H + c] = hval;
            }
        }
        if (tid == 0) { let_lds[uu] = tt; let_lds[vv] = tt; }
        __syncthreads();
    }
}

// ---------------------------------------------------------------------------
extern "C" void kernel_launch(void* const* d_in, const int* in_sizes, int n_in,
                              void* d_out, int out_size, void* d_ws, size_t ws_size,
                              hipStream_t stream)
{
    const int*   u        = (const int*)d_in[0];
    const int*   v        = (const int*)d_in[1];
    const float* t        = (const float*)d_in[2];
    const int*   k        = (const int*)d_in[3];
    const int*   u_others = (const int*)d_in[4];
    const int*   v_others = (const int*)d_in[5];
    const float* A        = (const float*)d_in[6];
    const float* S        = (const float*)d_in[7];
    const float* emb      = (const float*)d_in[8];
    const float* lastt    = (const float*)d_in[9];
    const float* W_S      = (const float*)d_in[10];
    const float* W_R      = (const float*)d_in[11];
    const float* W_t      = (const float*)d_in[12];
    const float* W_h      = (const float*)d_in[13];
    const float* b_h      = (const float*)d_in[14];
    const float* psi      = (const float*)d_in[15];
    const float* W_om     = (const float*)d_in[16];
    const float* b_om     = (const float*)d_in[17];
    (void)in_sizes; (void)n_in; (void)out_size; (void)ws_size;

    float* wsf   = (float*)d_ws;
    float* h_tab = wsf;                         // N*H
    float* d0    = wsf + (size_t)N * H;         // N
    float* d1    = d0 + N;                      // N
    float* sumv  = d1 + N;                      // 128
    float* nbre  = sumv + 128;                  // 128*MAXD
    int*   deg   = (int*)(nbre + 128 * MAXD);   // 128
    int*   nbri  = deg + 128;                   // 128*MAXD

    float* out    = (float*)d_out;
    float* lamout = out;            // [64]
    float* svout  = out + NEV;      // [20]
    float* z_out  = out + NEV + SS; // [N*H]

    hipMemsetAsync(deg, 0, 128 * sizeof(int), stream);
    k_emb<<<N / RPB, 512, 0, stream>>>(emb, W_h, b_h, W_om, h_tab, z_out, d0, d1);
    k_nbr<<<128, 256, 0, stream>>>(u, v, A, S, deg, sumv, nbri, nbre);
    k_lam<<<1, 64, 0, stream>>>(u, v, k, d0, d1, psi, b_om, lamout);
    k_surv<<<SS, 64, 0, stream>>>(u, v, u_others, v_others, d0, d1, psi, b_om, svout);
    k_seq<<<1, 512, 0, stream>>>(u, v, t, lastt, W_S, W_R, W_t, W_h, b_h,
                                 deg, sumv, nbri, nbre, h_tab, z_out);
}

// Round 2
// 200.951 us; speedup vs baseline: 2.5316x; 2.5316x over previous
//
#include <hip/hip_runtime.h>
#include <math.h>

#define N 8192
#define H 128
#define NEV 64
#define SS 20
#define MAXD 512
#define MAXDIRTY 128   // nd <= min(deg, 2*NEV-2) < 128 always
#define RPB 32         // rows per block in k_emb

// ---------------------------------------------------------------------------
// k_emb: h_tab[n][c] = sum_c' emb[n][c'] * W_h[c][c'] + b_h[c]
//        z_out[n] = emb[n] (copy), d0/d1[n] = emb[n] . (W_om[k][:H]+W_om[k][H:])
// ---------------------------------------------------------------------------
__global__ __launch_bounds__(512) void k_emb(
    const float* __restrict__ emb, const float* __restrict__ W_h,
    const float* __restrict__ b_h, const float* __restrict__ W_om,
    float* __restrict__ h_tab, float* __restrict__ z_out,
    float* __restrict__ d0, float* __restrict__ d1)
{
    const int tid = threadIdx.x;
    const int c = tid & 127;
    const int s = tid >> 7;             // 0..3
    const int r0 = blockIdx.x * RPB;

    __shared__ __align__(16) float z4[4 * 128];
    __shared__ float pr[8 * 128];       // [s][rr][c]

    float whr[32];
#pragma unroll
    for (int i = 0; i < 32; ++i) whr[i] = W_h[c * H + s * 32 + i];
    const float bh_c = b_h[c];

    const int lane = tid & 63;
    const int wid = tid >> 6;           // 0..7 (waves)
    const int kof = (wid >= 4) ? 256 : 0;
    const float wk_l = W_om[kof + lane]      + W_om[kof + 128 + lane];
    const float wk_h = W_om[kof + 64 + lane] + W_om[kof + 192 + lane];

    for (int b = 0; b < RPB / 4; ++b) {
        const int rbase = r0 + b * 4;
        __syncthreads();                           // protect z4/pr reuse
        const float zv = emb[(size_t)rbase * H + tid];
        z4[tid] = zv;
        z_out[(size_t)rbase * H + tid] = zv;
        __syncthreads();

#pragma unroll
        for (int rr = 0; rr < 4; ++rr) {
            float a = 0.f;
#pragma unroll
            for (int i4 = 0; i4 < 8; ++i4) {
                const float4 zz = *(const float4*)&z4[rr * 128 + s * 32 + i4 * 4];
                a += zz.x * whr[i4 * 4] + zz.y * whr[i4 * 4 + 1] +
                     zz.z * whr[i4 * 4 + 2] + zz.w * whr[i4 * 4 + 3];
            }
            pr[(s * 4 + rr) * 128 + c] = a;
        }

        {
            const int rr = wid & 3;
            float val = z4[rr * 128 + lane] * wk_l + z4[rr * 128 + 64 + lane] * wk_h;
#pragma unroll
            for (int off = 32; off > 0; off >>= 1) val += __shfl_xor(val, off);
            if (lane == 0) {
                if (wid < 4) d0[rbase + rr] = val;
                else         d1[rbase + rr] = val;
            }
        }
        __syncthreads();
        {
            const int rr = s;
            const float h = pr[(0 * 4 + rr) * 128 + c] + pr[(1 * 4 + rr) * 128 + c] +
                            pr[(2 * 4 + rr) * 128 + c] + pr[(3 * 4 + rr) * 128 + c] + bh_c;
            h_tab[(size_t)(rbase + rr) * H + c] = h;
        }
    }
}

// ---------------------------------------------------------------------------
// k_nbr: compact neighbor lists for the 128 (event,side) rows.
// slot = e*2+side; side0 -> row v[e], side1 -> row u[e].
// ---------------------------------------------------------------------------
__global__ __launch_bounds__(256) void k_nbr(
    const int* __restrict__ u, const int* __restrict__ v,
    const float* __restrict__ A, const float* __restrict__ S,
    int* __restrict__ deg, float* __restrict__ sumv,
    int* __restrict__ nbr_i, float* __restrict__ nbr_e)
{
    const int slot = blockIdx.x;
    const int e = slot >> 1, side = slot & 1;
    const int row = (side == 0) ? v[e] : u[e];
    const size_t base = (size_t)row * N;
    const int tid = threadIdx.x;
    float lsum = 0.f;
    for (int j = tid; j < N; j += 256) {
        if (A[base + j] > 0.f) {
            const float ev = expf(S[base + j]);
            lsum += ev;
            const int p = atomicAdd(&deg[slot], 1);
            if (p < MAXD) {
                nbr_i[slot * MAXD + p] = j;
                nbr_e[slot * MAXD + p] = ev;
            }
        }
    }
    __shared__ float rs[256];
    rs[tid] = lsum;
    __syncthreads();
    for (int off = 128; off > 0; off >>= 1) {
        if (tid < off) rs[tid] += rs[tid + off];
        __syncthreads();
    }
    if (tid == 0) sumv[slot] = rs[0];
}

// ---------------------------------------------------------------------------
// k_fe: fe[n] = first event index that updates node n (both u and v rows).
// fe pre-initialized to 0x7f7f7f7f by memset.
// ---------------------------------------------------------------------------
__global__ __launch_bounds__(128) void k_fe(
    const int* __restrict__ u, const int* __restrict__ v, int* __restrict__ fe)
{
    const int tid = threadIdx.x;
    if (tid < 2 * NEV) {
        const int e = tid >> 1;
        const int node = (tid & 1) ? v[e] : u[e];
        atomicMin(&fe[node], e);
    }
}

// ---------------------------------------------------------------------------
// k_dirty: per slot, list of neighbors whose row gets updated before event e.
// Order nondeterministic (atomicAdd) but only feeds fmax -> result exact.
// ---------------------------------------------------------------------------
__global__ __launch_bounds__(64) void k_dirty(
    const int* __restrict__ deg, const float* __restrict__ sumv,
    const int* __restrict__ nbr_i, const float* __restrict__ nbr_e,
    const int* __restrict__ fe,
    int* __restrict__ dcnt, int* __restrict__ dl_i, float* __restrict__ dl_q)
{
    const int slot = blockIdx.x;
    const int e = slot >> 1;
    const int d = min(deg[slot], MAXD);
    const float rinv = 1.0f / (sumv[slot] + 1e-7f);
    for (int j0 = threadIdx.x; j0 < d; j0 += 64) {
        const int j = nbr_i[slot * MAXD + j0];
        if (fe[j] < e) {
            const int p = atomicAdd(&dcnt[slot], 1);
            if (p < MAXDIRTY) {
                dl_i[slot * MAXDIRTY + p] = j;
                dl_q[slot * MAXDIRTY + p] = nbr_e[slot * MAXD + j0] * rinv;
            }
        }
    }
}

// ---------------------------------------------------------------------------
// k_mstat: Mstat[slot][c] = max over neighbors j with fe[j] >= e of q_j*h0[j][c]
// (-inf if none). These rows are untouched until after event e -> static.
// ---------------------------------------------------------------------------
__global__ __launch_bounds__(128) void k_mstat(
    const int* __restrict__ deg, const float* __restrict__ sumv,
    const int* __restrict__ nbr_i, const float* __restrict__ nbr_e,
    const int* __restrict__ fe, const float* __restrict__ h_tab,
    float* __restrict__ Mstat)
{
    const int slot = blockIdx.x;
    const int e = slot >> 1;
    const int c = threadIdx.x;
    const int d = min(deg[slot], MAXD);
    const float rinv = 1.0f / (sumv[slot] + 1e-7f);
    float m = -INFINITY;
    for (int j0 = 0; j0 < d; ++j0) {
        const int j = nbr_i[slot * MAXD + j0];
        if (fe[j] >= e) {
            const float q = nbr_e[slot * MAXD + j0] * rinv;
            m = fmaxf(m, q * h_tab[(size_t)j * H + c]);
        }
    }
    Mstat[slot * H + c] = m;
}

// ---------------------------------------------------------------------------
// k_lam / k_surv: rate evaluations from precomputed d0/d1.
// ---------------------------------------------------------------------------
__global__ __launch_bounds__(64) void k_lam(
    const int* __restrict__ u, const int* __restrict__ v, const int* __restrict__ k,
    const float* __restrict__ d0, const float* __restrict__ d1,
    const float* __restrict__ psi, const float* __restrict__ b_om,
    float* __restrict__ out)
{
    const int b = threadIdx.x;
    if (b < NEV) {
        const int kk = k[b];
        const float* dk = kk ? d1 : d0;
        const float g = 0.5f * (dk[u[b]] + dk[v[b]]) + b_om[kk];
        const float ps = psi[kk];
        const float x = fminf(75.f, fmaxf(-75.f, g / ps));
        out[b] = ps * log1pf(expf(x));
    }
}

__global__ __launch_bounds__(64) void k_surv(
    const int* __restrict__ u, const int* __restrict__ v,
    const int* __restrict__ u_o, const int* __restrict__ v_o,
    const float* __restrict__ d0, const float* __restrict__ d1,
    const float* __restrict__ psi, const float* __restrict__ b_om,
    float* __restrict__ out)
{
    const int s = blockIdx.x;   // 0..SS-1
    const int b = threadIdx.x;  // 0..63
    const float p0 = psi[0], p1 = psi[1], bo0 = b_om[0], bo1 = b_om[1];
    const int vo = v_o[b * SS + s], uo = u_o[b * SS + s];
    float g, x;
    g = 0.5f * (d0[u[b]] + d0[vo]) + bo0; x = fminf(75.f, fmaxf(-75.f, g / p0));
    const float ru0 = p0 * log1pf(expf(x));
    g = 0.5f * (d1[u[b]] + d1[vo]) + bo1; x = fminf(75.f, fmaxf(-75.f, g / p1));
    const float ru1 = p1 * log1pf(expf(x));
    g = 0.5f * (d1[v[b]] + d1[uo]) + bo1; x = fminf(75.f, fmaxf(-75.f, g / p1));
    const float rv1 = p1 * log1pf(expf(x));
    float val = 2.f * (ru0 + ru1) + rv1;
#pragma unroll
    for (int off = 32; off > 0; off >>= 1) val += __shfl_xor(val, off);
    if (b == 0) out[s] = val / (float)SS;
}

// ---------------------------------------------------------------------------
// k_seq: sequential 64-event scan. One block, 512 threads, 5 barriers/event.
// Phase A uses precomputed Mstat (prefetched 1 event ahead) + rare dirty fixes.
// z rows prefetched 1 event ahead, patched from LDS znw when just-updated.
// W_S/W_R/W_h pinned in registers via asm liveness.
// ---------------------------------------------------------------------------
__global__ __launch_bounds__(512, 1) void k_seq(
    const int* __restrict__ u, const int* __restrict__ v, const float* __restrict__ t,
    const float* __restrict__ lastt,
    const float* __restrict__ W_S, const float* __restrict__ W_R,
    const float* __restrict__ W_t, const float* __restrict__ W_h,
    const float* __restrict__ b_h,
    const int* __restrict__ deg, const int* __restrict__ dcnt,
    const int* __restrict__ dl_i, const float* __restrict__ dl_q,
    const float* __restrict__ Mstat,
    float* __restrict__ h_tab, float* __restrict__ z_out)
{
    const int tid = threadIdx.x;
    const int c = tid & 127;
    const int s = tid >> 7;                 // 0..3

    __shared__ float let_lds[N];            // 32 KB
    __shared__ __align__(16) float hz[128 * 4];   // [c']{hs0,hs1,z_v,z_u}
    __shared__ float pr[8 * 128];           // [(s*2+r)][c] partials
    __shared__ __align__(8) float znw[128 * 2];   // [c']{znew_v, znew_u}
    __shared__ int   ev_u[NEV], ev_v[NEV];
    __shared__ float ev_t[NEV];
    __shared__ int   deg_lds[2 * NEV], dcnt_lds[2 * NEV];

    float wsr[32], wrr[32], whr[32];
#pragma unroll
    for (int i = 0; i < 32; ++i) {
        wsr[i] = W_S[c * H + s * 32 + i];
        wrr[i] = W_R[c * H + s * 32 + i];
        whr[i] = W_h[c * H + s * 32 + i];
    }
    const float wt_c = W_t[c];
    const float bh_c = b_h[c];

    for (int i = tid; i < N; i += 512) let_lds[i] = lastt[i];
    if (tid < NEV) { ev_u[tid] = u[tid]; ev_v[tid] = v[tid]; ev_t[tid] = t[tid]; }
    if (tid < 2 * NEV) { deg_lds[tid] = deg[tid]; dcnt_lds[tid] = dcnt[tid]; }
    __syncthreads();

    const int side = tid >> 7;              // meaningful for tid<256
    const int rz = (tid >> 7) & 1;          // meaningful for tid>=256

    // prefetches for event 0
    float mpf = 0.f, zpf = 0.f;
    if (tid < 256) {
        mpf = Mstat[side * H + c];
    } else {
        const int row0 = rz ? ev_u[0] : ev_v[0];
        zpf = z_out[(size_t)row0 * H + c];
    }

    for (int e = 0; e < NEV; ++e) {
        // pin weights live across the loop (prevent rematerialization)
#pragma unroll
        for (int i = 0; i < 32; ++i)
            asm volatile("" : "+v"(wsr[i]), "+v"(wrr[i]), "+v"(whr[i]));

        const int uu = ev_u[e], vv = ev_v[e];
        const float tt = ev_t[e];

        // ---- Phase A ----
        if (tid < 256) {
            const int slot = e * 2 + side;
            float m = mpf;
            const int nd = min(dcnt_lds[slot], MAXDIRTY);
            for (int p = 0; p < nd; ++p) {
                const int j = dl_i[slot * MAXDIRTY + p];
                const float q = dl_q[slot * MAXDIRTY + p];
                m = fmaxf(m, q * h_tab[(size_t)j * H + c]);
            }
            hz[c * 4 + side] = (deg_lds[slot] > 0) ? 1.0f / (1.0f + __expf(-m)) : 0.0f;
            if (e + 1 < NEV) mpf = Mstat[((e + 1) * 2 + side) * H + c];  // prefetch
        } else {
            const int row = rz ? uu : vv;
            float zv;
            if (e > 0 && row == ev_u[e - 1])      zv = znw[c * 2 + 1];
            else if (e > 0 && row == ev_v[e - 1]) zv = znw[c * 2 + 0];
            else                                   zv = zpf;
            hz[c * 4 + 2 + rz] = zv;
        }
        __syncthreads();   // B1: hz ready

        // ---- Phase B partial: g[r][c] partial over s-chunk ----
        {
            float a0 = 0.f, a1 = 0.f;
#pragma unroll
            for (int i = 0; i < 32; ++i) {
                const float4 vz = *(const float4*)&hz[(s * 32 + i) * 4];
                a0 += vz.x * wsr[i] + vz.z * wrr[i];
                a1 += vz.y * wsr[i] + vz.w * wrr[i];
            }
            pr[(s * 2 + 0) * 128 + c] = a0;
            pr[(s * 2 + 1) * 128 + c] = a1;
        }
        __syncthreads();   // B2: partials ready

        if (tid < 256) {
            const int r = tid >> 7;
            float g = pr[(0 * 2 + r) * 128 + c] + pr[(1 * 2 + r) * 128 + c] +
                      pr[(2 * 2 + r) * 128 + c] + pr[(3 * 2 + r) * 128 + c];
            const float dt = tt - ((r == 0) ? let_lds[uu] : let_lds[vv]);
            g += dt * wt_c;
            znw[c * 2 + r] = 1.0f / (1.0f + __expf(-g));
        }
        __syncthreads();   // B3: znw ready

        // prefetch next event's z rows (safe: write to z_out happens after B4)
        if (tid >= 256 && e + 1 < NEV) {
            const int nrow = rz ? ev_u[e + 1] : ev_v[e + 1];
            zpf = z_out[(size_t)nrow * H + c];
        }

        // ---- Phase C partial: h_new[r][c] partial ----
        {
            float a0 = 0.f, a1 = 0.f;
#pragma unroll
            for (int i = 0; i < 32; ++i) {
                const float2 zz = *(const float2*)&znw[(s * 32 + i) * 2];
                a0 += zz.x * whr[i];
                a1 += zz.y * whr[i];
            }
            pr[(s * 2 + 0) * 128 + c] = a0;
            pr[(s * 2 + 1) * 128 + c] = a1;
        }
        __syncthreads();   // B4: partials ready

        if (tid < 256) {
            const int r = tid >> 7;
            const int row = (r == 0) ? vv : uu;
            if (!(uu == vv && r == 0)) {       // duplicate rows: last index wins
                const float hval = pr[(0 * 2 + r) * 128 + c] + pr[(1 * 2 + r) * 128 + c] +
                                   pr[(2 * 2 + r) * 128 + c] + pr[(3 * 2 + r) * 128 + c] + bh_c;
                z_out[(size_t)row * H + c] = znw[c * 2 + r];
                h_tab[(size_t)row * H + c] = hval;
            }
        }
        if (tid == 0) { let_lds[uu] = tt; let_lds[vv] = tt; }
        __syncthreads();   // B5: writes + let visible before next phase A
    }
}

// ---------------------------------------------------------------------------
extern "C" void kernel_launch(void* const* d_in, const int* in_sizes, int n_in,
                              void* d_out, int out_size, void* d_ws, size_t ws_size,
                              hipStream_t stream)
{
    const int*   u        = (const int*)d_in[0];
    const int*   v        = (const int*)d_in[1];
    const float* t        = (const float*)d_in[2];
    const int*   k        = (const int*)d_in[3];
    const int*   u_others = (const int*)d_in[4];
    const int*   v_others = (const int*)d_in[5];
    const float* A        = (const float*)d_in[6];
    const float* S        = (const float*)d_in[7];
    const float* emb      = (const float*)d_in[8];
    const float* lastt    = (const float*)d_in[9];
    const float* W_S      = (const float*)d_in[10];
    const float* W_R      = (const float*)d_in[11];
    const float* W_t      = (const float*)d_in[12];
    const float* W_h      = (const float*)d_in[13];
    const float* b_h      = (const float*)d_in[14];
    const float* psi      = (const float*)d_in[15];
    const float* W_om     = (const float*)d_in[16];
    const float* b_om     = (const float*)d_in[17];
    (void)in_sizes; (void)n_in; (void)out_size; (void)ws_size;

    float* wsf   = (float*)d_ws;
    float* h_tab = wsf;                          // N*H
    float* d0    = h_tab + (size_t)N * H;        // N
    float* d1    = d0 + N;                       // N
    float* sumv  = d1 + N;                       // 128
    float* nbre  = sumv + 128;                   // 128*MAXD
    float* Mstat = nbre + 128 * MAXD;            // 128*128
    float* dl_q  = Mstat + 128 * H;              // 128*MAXDIRTY
    int*   deg   = (int*)(dl_q + 128 * MAXDIRTY);// 128
    int*   dcnt  = deg + 128;                    // 128
    int*   nbri  = dcnt + 128;                   // 128*MAXD
    int*   dl_i  = nbri + 128 * MAXD;            // 128*MAXDIRTY
    int*   fe    = dl_i + 128 * MAXDIRTY;        // N

    float* out    = (float*)d_out;
    float* lamout = out;            // [64]
    float* svout  = out + NEV;      // [20]
    float* z_out  = out + NEV + SS; // [N*H]

    hipMemsetAsync(deg, 0, 2 * 128 * sizeof(int), stream);     // deg + dcnt
    hipMemsetAsync(fe, 0x7f, N * sizeof(int), stream);         // fe = big

    k_emb<<<N / RPB, 512, 0, stream>>>(emb, W_h, b_h, W_om, h_tab, z_out, d0, d1);
    k_nbr<<<128, 256, 0, stream>>>(u, v, A, S, deg, sumv, nbri, nbre);
    k_fe<<<1, 128, 0, stream>>>(u, v, fe);
    k_dirty<<<128, 64, 0, stream>>>(deg, sumv, nbri, nbre, fe, dcnt, dl_i, dl_q);
    k_mstat<<<128, 128, 0, stream>>>(deg, sumv, nbri, nbre, fe, h_tab, Mstat);
    k_lam<<<1, 64, 0, stream>>>(u, v, k, d0, d1, psi, b_om, lamout);
    k_surv<<<SS, 64, 0, stream>>>(u, v, u_others, v_others, d0, d1, psi, b_om, svout);
    k_seq<<<1, 512, 0, stream>>>(u, v, t, lastt, W_S, W_R, W_t, W_h, b_h,
                                 deg, dcnt, dl_i, dl_q, Mstat, h_tab, z_out);
}